// Round 8
// baseline (80.930 us; speedup 1.0000x reference)
//
#include <hip/hip_runtime.h>
#include <hip/hip_bf16.h>
#include <math.h>

// NoisyTopExpertsPerItemRouter: B=8,S=4096,D=1024,E=64,K=2
#define B_ 8
#define S_ 4096
#define D_ 1024
#define E_ 64
#define NOISE_STD 0.015625f     // max(1/64, 1e-6)
#define INV_NOISE_STD 64.0f
#define OUT_GATES (B_ * S_ * E_)   // 2097152
#define NBLK 2048                  // main grid = S_/2

typedef __attribute__((ext_vector_type(8))) short short8;
typedef __attribute__((ext_vector_type(4))) float f32x4;

// workspace layout (float offsets)
// [0 .. 32768): Wg as bf16 [64][1024] (ushort)
#define WS_GW   32768                    // GW[64]
#define WS_BW   32832                    // BW[64]
#define WS_PART 32896                    // part[2048][644] plain per-block records
#define PART_STRIDE 644                  // 512 imp + 64 sgn + 64 cnt + c1 + c2 (+2 pad)
#define WS_TOT  (WS_PART + NBLK * PART_STRIDE)   // totals[642]
#define N_TOT   642

__device__ __forceinline__ float wave_sum64(float v) {
#pragma unroll
  for (int o = 32; o > 0; o >>= 1) v += __shfl_xor(v, o);
  return v;
}

// ---------------- prep: Wg(bf16) = gamma*W, GW/BW reductions, zero totals ---
__global__ void router_prep(const float* __restrict__ W,
                            const float* __restrict__ gamma,
                            const float* __restrict__ beta,
                            float* __restrict__ ws) {
  if (blockIdx.x >= E_) {
    for (int i = threadIdx.x; i < N_TOT; i += 256) ws[WS_TOT + i] = 0.0f;
    return;
  }
  const int e = blockIdx.x;
  unsigned short* wgb = (unsigned short*)ws;
  float gw = 0.0f, bw = 0.0f;
  for (int d = threadIdx.x; d < D_; d += 256) {
    float wv = W[e * D_ + d];
    float pv = gamma[d] * wv;
    union { __hip_bfloat16 h; unsigned short u; } cv;
    cv.h = __float2bfloat16(pv);
    wgb[e * D_ + d] = cv.u;
    gw += __bfloat162float(cv.h);   // sum of ROUNDED values (consistency)
    bw += beta[d] * wv;
  }
  __shared__ float sred[8];
  gw = wave_sum64(gw);
  bw = wave_sum64(bw);
  const int w = threadIdx.x >> 6, lane = threadIdx.x & 63;
  if (lane == 0) { sred[w] = gw; sred[4 + w] = bw; }
  __syncthreads();
  if (threadIdx.x == 0) {
    ws[WS_GW + e] = sred[0] + sred[1] + sred[2] + sred[3];
    ws[WS_BW + e] = sred[4] + sred[5] + sred[6] + sred[7];
  }
}

// ---------------- main: K-split-4, queued X AND B, counted vmcnt, NO atomics -
// block = 256 thr = 4 waves; block owns 16 rows (r: b=r&7, sl=r>>3, s=2*bid+sl).
// Wave w = K-chunk [256w,256w+256) for ALL 16 rows x 64 experts (4 MFMA chains).
// Register queues: qx[4] (X, issue j+4), qb[2] (B, issue j+2) -> every consumer
// waits on a COUNTED vmcnt, never vmcnt(0). Phase 2 writes a per-block 642-float
// record with PLAIN stores (no global atomics -- the R3-R7 ~50us serializer).
__global__ void __launch_bounds__(256, 4)
router_main(const float* __restrict__ X, const float* __restrict__ noise,
            float* __restrict__ out, float* __restrict__ ws) {
  __shared__ __align__(16) float Pbuf[3072];   // acc exchange; then gcl/gnl
  __shared__ __align__(16) float Lg[1088];     // [16][68] logits
  __shared__ float svp[4][16], sv2p[4][16];
  __shared__ float cntl[64];
  __shared__ float red4[4];
  f32x4* Pp  = (f32x4*)Pbuf;   // [4 chains][3 srcs][64 lanes] = 12288B
  float* gcl = Pbuf;           // epilogue aliases (exchange reads done)
  float* gnl = Pbuf + 1088;
  float* pl  = Lg;             // per-lane read-then-write -> safe alias

  const int t = threadIdx.x;
  const int w = t >> 6, lane = t & 63;
  const int lrow = lane & 15, kh = lane >> 4;
  const int bid = blockIdx.x;
  const int s0 = bid * 2;

  // A-row this lane loads; wave's K-chunk
  const int b_mf = lrow & 7, sl_mf = lrow >> 3;
  const int wko = w * 256 + kh * 8;
  const float* __restrict__ xp =
      X + ((size_t)b_mf * S_ + (size_t)(s0 + sl_mf)) * D_ + wko;
  const unsigned short* __restrict__ wgb = (const unsigned short*)ws;
  const unsigned short* __restrict__ bp0 = wgb + (0  + lrow) * D_ + wko;
  const unsigned short* __restrict__ bp1 = wgb + (16 + lrow) * D_ + wko;
  const unsigned short* __restrict__ bp2 = wgb + (32 + lrow) * D_ + wko;
  const unsigned short* __restrict__ bp3 = wgb + (48 + lrow) * D_ + wko;

  const float gwv = ws[WS_GW + 16 * w + lrow];
  const float bwv = ws[WS_BW + 16 * w + lrow];

  // epilogue indices + EARLY noise load (oldest in queue; lands during GEMM)
  const int rr_e = lane >> 4, j_e = lane & 15;
  const int r_e = w * 4 + rr_e;
  const int b_e = r_e & 7, sl_e = r_e >> 3;
  const int s_e = s0 + sl_e;
  const float4 nv =
      *(const float4*)(noise + ((size_t)b_e * S_ + s_e) * E_ + 4 * j_e);

  // prologue: fill queues (X iters 0..3, B iters 0..1)
  float4 qx[4][2];
  short8 qb[2][4];
#pragma unroll
  for (int j = 0; j < 4; j++) {
    qx[j][0] = *(const float4*)(xp + j * 32);
    qx[j][1] = *(const float4*)(xp + j * 32 + 4);
  }
#pragma unroll
  for (int j = 0; j < 2; j++) {
    qb[j][0] = *(const short8*)(bp0 + j * 32);
    qb[j][1] = *(const short8*)(bp1 + j * 32);
    qb[j][2] = *(const short8*)(bp2 + j * 32);
    qb[j][3] = *(const short8*)(bp3 + j * 32);
  }

  float sv = 0.0f, sv2 = 0.0f;
  f32x4 acc0 = {0.f, 0.f, 0.f, 0.f};
  f32x4 acc1 = {0.f, 0.f, 0.f, 0.f};
  f32x4 acc2 = {0.f, 0.f, 0.f, 0.f};
  f32x4 acc3 = {0.f, 0.f, 0.f, 0.f};

#pragma unroll
  for (int j = 0; j < 8; ++j) {
    if (j + 4 < 8) {                       // issue X for iter j+4 (ring, no WAR)
      qx[(j + 4) & 3][0] = *(const float4*)(xp + (j + 4) * 32);
      qx[(j + 4) & 3][1] = *(const float4*)(xp + (j + 4) * 32 + 4);
    }
    float4 a0 = qx[j & 3][0];
    float4 a1 = qx[j & 3][1];

    union { short8 s8; __hip_bfloat162 h[4]; } u;
    u.h[0] = __float22bfloat162_rn(make_float2(a0.x, a0.y));
    u.h[1] = __float22bfloat162_rn(make_float2(a0.z, a0.w));
    u.h[2] = __float22bfloat162_rn(make_float2(a1.x, a1.y));
    u.h[3] = __float22bfloat162_rn(make_float2(a1.z, a1.w));

    acc0 = __builtin_amdgcn_mfma_f32_16x16x32_bf16(u.s8, qb[j & 1][0], acc0, 0, 0, 0);
    acc1 = __builtin_amdgcn_mfma_f32_16x16x32_bf16(u.s8, qb[j & 1][1], acc1, 0, 0, 0);
    acc2 = __builtin_amdgcn_mfma_f32_16x16x32_bf16(u.s8, qb[j & 1][2], acc2, 0, 0, 0);
    acc3 = __builtin_amdgcn_mfma_f32_16x16x32_bf16(u.s8, qb[j & 1][3], acc3, 0, 0, 0);

    if (j + 2 < 8) {                       // refill B slot just consumed
      qb[j & 1][0] = *(const short8*)(bp0 + (j + 2) * 32);
      qb[j & 1][1] = *(const short8*)(bp1 + (j + 2) * 32);
      qb[j & 1][2] = *(const short8*)(bp2 + (j + 2) * 32);
      qb[j & 1][3] = *(const short8*)(bp3 + (j + 2) * 32);
    }

    sv += (a0.x + a0.y) + (a0.z + a0.w) + (a1.x + a1.y) + (a1.z + a1.w);
    sv2 = fmaf(a0.x, a0.x, sv2); sv2 = fmaf(a0.y, a0.y, sv2);
    sv2 = fmaf(a0.z, a0.z, sv2); sv2 = fmaf(a0.w, a0.w, sv2);
    sv2 = fmaf(a1.x, a1.x, sv2); sv2 = fmaf(a1.y, a1.y, sv2);
    sv2 = fmaf(a1.w, a1.w, sv2); sv2 = fmaf(a1.z, a1.z, sv2);
  }

  // per-row LN stats partial (this wave's 256 k's): combine 4 kh lanes
  sv  += __shfl_xor(sv, 16);  sv  += __shfl_xor(sv, 32);
  sv2 += __shfl_xor(sv2, 16); sv2 += __shfl_xor(sv2, 32);
  if (lane < 16) { svp[w][lane] = sv; sv2p[w][lane] = sv2; }

  // publish partials for the 3 chains we don't own (chain c combined by wave c)
  if (w != 0) Pp[(0 * 3 + (w - 1)) * 64 + lane] = acc0;
  if (w != 1) Pp[(1 * 3 + (w - (w > 1))) * 64 + lane] = acc1;
  if (w != 2) Pp[(2 * 3 + (w - (w > 2))) * 64 + lane] = acc2;
  if (w != 3) Pp[(3 * 3 + w) * 64 + lane] = acc3;
  __syncthreads();

  // wave w combines chain w: own acc_w (K-chunk w) + 3 published partials
  f32x4 mine = (w == 0) ? acc0 : (w == 1) ? acc1 : (w == 2) ? acc2 : acc3;
  f32x4 asum = mine + Pp[(w * 3 + 0) * 64 + lane] +
               Pp[(w * 3 + 1) * 64 + lane] + Pp[(w * 3 + 2) * 64 + lane];

  const float svr  = (svp[0][lrow] + svp[1][lrow]) + (svp[2][lrow] + svp[3][lrow]);
  const float sv2r = (sv2p[0][lrow] + sv2p[1][lrow]) + (sv2p[2][lrow] + sv2p[3][lrow]);
  float mu = svr * (1.0f / (float)D_);
  float var = sv2r * (1.0f / (float)D_) - mu * mu;
  float rs = rsqrtf(var + 1e-5f);

  // C/D layout: col(expert-in-tile)=lane&15, row=(lane>>4)*4+i  [m89-verified]
#pragma unroll
  for (int i = 0; i < 4; i++) {
    const int rloc = kh * 4 + i;
    const float mui = __shfl(mu, kh * 4 + i);   // lane (kh*4+i) holds row kh*4+i
    const float rsi = __shfl(rs, kh * 4 + i);
    Lg[rloc * 68 + 16 * w + lrow] = rsi * (asum[i] - mui * gwv) + bwv;
  }
  if (t < 64) cntl[t] = 0.0f;
  __syncthreads();   // logits ready; Pp reads done -> gcl/gnl reusable

  // ---- epilogue: all 4 waves; wave w rows 4w..4w+3; lane=(rr,j), 4 experts --
  {
    const int r = r_e, b = b_e, s = s_e, j = j_e;
    float4 lv = *(const float4*)(Lg + r * 68 + 4 * j);
    float ln0 = fmaf(NOISE_STD, nv.x, lv.x);
    float ln1 = fmaf(NOISE_STD, nv.y, lv.y);
    float ln2 = fmaf(NOISE_STD, nv.z, lv.z);
    float ln3 = fmaf(NOISE_STD, nv.w, lv.w);

    // combined max+secondmax of noisy logits (m1 also shifts clean softmax)
    float m1 = ln0, m2 = -INFINITY;
    m2 = fmaxf(m2, fminf(m1, ln1)); m1 = fmaxf(m1, ln1);
    m2 = fmaxf(m2, fminf(m1, ln2)); m1 = fmaxf(m1, ln2);
    m2 = fmaxf(m2, fminf(m1, ln3)); m1 = fmaxf(m1, ln3);
#pragma unroll
    for (int o = 1; o <= 8; o <<= 1) {
      float o1 = __shfl_xor(m1, o), o2 = __shfl_xor(m2, o);
      m2 = fmaxf(fmaxf(m2, o2), fminf(m1, o1));
      m1 = fmaxf(m1, o1);
    }
    float ec0 = __expf(lv.x - m1), ec1 = __expf(lv.y - m1);
    float ec2 = __expf(lv.z - m1), ec3 = __expf(lv.w - m1);
    float en0 = __expf(ln0 - m1), en1 = __expf(ln1 - m1);
    float en2 = __expf(ln2 - m1), en3 = __expf(ln3 - m1);
    float sg = (ec0 + ec1) + (ec2 + ec3);
    float sn = (en0 + en1) + (en2 + en3);
#pragma unroll
    for (int o = 1; o <= 8; o <<= 1) {
      sg += __shfl_xor(sg, o);
      sn += __shfl_xor(sn, o);
    }
    const float rg = 1.0f / sg, rn = 1.0f / sn;
    float4 gnv = { en0 * rn, en1 * rn, en2 * rn, en3 * rn };
    float4 gcv = { ec0 * rg, ec1 * rg, ec2 * rg, ec3 * rg };
    float z0 = fminf(fmaxf((m2 - lv.x) * INV_NOISE_STD, -10.f), 10.f);
    float z1 = fminf(fmaxf((m2 - lv.y) * INV_NOISE_STD, -10.f), 10.f);
    float z2 = fminf(fmaxf((m2 - lv.z) * INV_NOISE_STD, -10.f), 10.f);
    float z3 = fminf(fmaxf((m2 - lv.w) * INV_NOISE_STD, -10.f), 10.f);
    float4 pv = { 0.5f * (1.0f + erff(z0 * 0.70710678118654752f)),
                  0.5f * (1.0f + erff(z1 * 0.70710678118654752f)),
                  0.5f * (1.0f + erff(z2 * 0.70710678118654752f)),
                  0.5f * (1.0f + erff(z3 * 0.70710678118654752f)) };

    *(float4*)(out + ((size_t)b * S_ + s) * E_ + 4 * j) = gnv;
    *(float4*)(gnl + r * 68 + 4 * j) = gnv;
    *(float4*)(gcl + r * 68 + 4 * j) = gcv;
    *(float4*)(pl  + r * 68 + 4 * j) = pv;
    // top-1 count via equality (ties vanishingly rare; softmax is monotone)
    if (ln0 == m1) atomicAdd(&cntl[4 * j + 0], 1.0f);
    if (ln1 == m1) atomicAdd(&cntl[4 * j + 1], 1.0f);
    if (ln2 == m1) atomicAdd(&cntl[4 * j + 2], 1.0f);
    if (ln3 == m1) atomicAdd(&cntl[4 * j + 3], 1.0f);
  }
  __syncthreads();

  // ---- phase 2: block-level reductions -> PLAIN per-block record stores ----
  float* prt = ws + WS_PART + (size_t)bid * PART_STRIDE;
  {
    int b0i = t >> 6, e0i = t & 63;
    prt[t] = gcl[b0i * 68 + e0i] + gcl[(8 + b0i) * 68 + e0i];
    int p1 = t + 256;
    int b1i = p1 >> 6, e1i = p1 & 63;
    prt[p1] = gcl[b1i * 68 + e1i] + gcl[(8 + b1i) * 68 + e1i];
  }
  if (t < 64) {
    float sgn = 0.0f;
#pragma unroll
    for (int r = 0; r < 16; r++) sgn += gnl[r * 68 + t];
    prt[512 + t] = sgn;
  } else if (t < 128) {
    prt[576 + (t - 64)] = cntl[t - 64];
  } else {
    const int idx = t - 128;            // [0,128): sl = idx>>6, e = idx&63
    const int slc = idx >> 6, e = idx & 63;
    float P = 0.0f;
#pragma unroll
    for (int b = 0; b < 8; b++) P += pl[(slc * 8 + b) * 68 + e];
    float c1 = P * 0.125f;
    float c2 = c1 * c1;
    c1 = wave_sum64(c1);
    c2 = wave_sum64(c2);
    if (lane == 0) { red4[(w - 2) * 2] = c1; red4[(w - 2) * 2 + 1] = c2; }
  }
  __syncthreads();
  if (t == 0) {
    prt[640] = red4[0] + red4[2];
    prt[641] = red4[1] + red4[3];
  }
}

// ---------------- reduce: 8 blocks sum 256 records each -> 5K atomics -------
__global__ void router_reduce(float* __restrict__ ws) {
  const int t = threadIdx.x;
  if (t >= N_TOT) return;
  const int base = blockIdx.x * 256;
  const float* p = ws + WS_PART + (size_t)base * PART_STRIDE + t;
  float acc = 0.0f;
#pragma unroll 4
  for (int i = 0; i < 256; ++i) acc += p[(size_t)i * PART_STRIDE];
  atomicAdd(&ws[WS_TOT + t], acc);
}

// ---------------- finalize: 3 scalar losses from totals ---------------------
__global__ void router_final(const float* __restrict__ ws, float* __restrict__ out) {
  const int lane = threadIdx.x;  // 64 threads = 1 wave
  const float* tot = ws + WS_TOT;
  float impsum = 0.0f;
  for (int b = 0; b < B_; ++b) {
    float v = tot[b * 64 + lane];
    float sfull = wave_sum64(v);
    float mean = sfull * (1.0f / 64.0f);
    float d = v - mean;
    float ss = wave_sum64(d * d);
    impsum += (ss / 63.0f) / (mean * mean);
  }
  float importance = impsum * (1.0f / (float)B_);

  const float N = (float)(S_ * E_);
  float meanp = tot[640] / N;
  float varp = tot[641] / N - meanp * meanp;
  float load = varp / (meanp * meanp);

  const float inv_rows = 1.0f / (float)(B_ * S_);
  float te = (tot[576 + lane] * inv_rows) * (tot[512 + lane] * inv_rows);
  float gs = wave_sum64(te) * (float)E_;

  if (lane == 0) {
    out[OUT_GATES + 0] = importance + load;  // aux (GSHARD_W = 0)
    out[OUT_GATES + 1] = gs;
    out[OUT_GATES + 2] = importance;
    out[OUT_GATES + 3] = load;
  }
}

extern "C" void kernel_launch(void* const* d_in, const int* in_sizes, int n_in,
                              void* d_out, int out_size, void* d_ws, size_t ws_size,
                              hipStream_t stream) {
  (void)in_sizes; (void)n_in; (void)out_size; (void)ws_size;
  const float* X     = (const float*)d_in[0];
  const float* noise = (const float*)d_in[1];
  const float* gamma = (const float*)d_in[2];
  const float* beta  = (const float*)d_in[3];
  const float* W     = (const float*)d_in[4];
  float* out = (float*)d_out;
  float* ws  = (float*)d_ws;

  router_prep<<<dim3(E_ + 1), dim3(256), 0, stream>>>(W, gamma, beta, ws);
  router_main<<<dim3(NBLK), dim3(256), 0, stream>>>(X, noise, out, ws);
  router_reduce<<<dim3(8), dim3(704), 0, stream>>>(ws);
  router_final<<<dim3(1), dim3(64), 0, stream>>>(ws, out);
}

// Round 9
// 60.200 us; speedup vs baseline: 1.3443x; 1.3443x over previous
//
#include <hip/hip_runtime.h>
#include <hip/hip_bf16.h>
#include <math.h>

// NoisyTopExpertsPerItemRouter: B=8,S=4096,D=1024,E=64,K=2
#define B_ 8
#define S_ 4096
#define D_ 1024
#define E_ 64
#define NOISE_STD 0.015625f     // max(1/64, 1e-6)
#define INV_NOISE_STD 64.0f
#define OUT_GATES (B_ * S_ * E_)   // 2097152
#define NBLK 1024                  // main grid = S_/4 (32 rows per block)

typedef __attribute__((ext_vector_type(8))) short short8;
typedef __attribute__((ext_vector_type(4))) float f32x4;

// workspace layout (float offsets)
// [0 .. 32768): Wg as bf16 [64][1024] (ushort)
#define WS_GW   32768                    // GW[64]
#define WS_BW   32832                    // BW[64]
#define WS_PART 32896                    // part[1024][644] per-block records
#define PART_STRIDE 644                  // 512 imp + 64 sgn + 64 cnt + c1 + c2
#define WS_TOT  (WS_PART + NBLK * PART_STRIDE)
#define N_TOT   642

__device__ __forceinline__ float wave_sum64(float v) {
#pragma unroll
  for (int o = 32; o > 0; o >>= 1) v += __shfl_xor(v, o);
  return v;
}

// ---------------- prep: Wg(bf16) = gamma*W, GW/BW reductions, zero totals ---
__global__ void router_prep(const float* __restrict__ W,
                            const float* __restrict__ gamma,
                            const float* __restrict__ beta,
                            float* __restrict__ ws) {
  if (blockIdx.x >= E_) {
    for (int i = threadIdx.x; i < N_TOT; i += 256) ws[WS_TOT + i] = 0.0f;
    return;
  }
  const int e = blockIdx.x;
  unsigned short* wgb = (unsigned short*)ws;
  float gw = 0.0f, bw = 0.0f;
  for (int d = threadIdx.x; d < D_; d += 256) {
    float wv = W[e * D_ + d];
    float pv = gamma[d] * wv;
    union { __hip_bfloat16 h; unsigned short u; } cv;
    cv.h = __float2bfloat16(pv);
    wgb[e * D_ + d] = cv.u;
    gw += __bfloat162float(cv.h);   // sum of ROUNDED values (consistency)
    bw += beta[d] * wv;
  }
  __shared__ float sred[8];
  gw = wave_sum64(gw);
  bw = wave_sum64(bw);
  const int w = threadIdx.x >> 6, lane = threadIdx.x & 63;
  if (lane == 0) { sred[w] = gw; sred[4 + w] = bw; }
  __syncthreads();
  if (threadIdx.x == 0) {
    ws[WS_GW + e] = sred[0] + sred[1] + sred[2] + sred[3];
    ws[WS_BW + e] = sred[4] + sred[5] + sred[6] + sred[7];
  }
}

// ---------------- main: 32-row blocks, B shared via L1, full-K waves --------
// block = 512 thr = 8 waves; owns 32 rows (r: b=r&7, sl=r>>3, s=4*bid+sl).
// Wave w: row-group rg=w>>2 (16 rows), expert tile et=w&3 (16 experts), FULL K
// -> acc = 1 f32x4, no partial exchange. Waves rg=0/1 of the same et issue
// identical B addresses in lockstep -> L1 serves the second (B L2-traffic
// halves vs R7 per row). X staged once to LDS ([row][68], 16B-aligned b128
// A-frags); X reg-queue depth 2 + LDS dbuf; B ring 2 steps ahead -> all
// consumer waits are COUNTED vmcnt (5-6), never 0.
__global__ void __launch_bounds__(512, 4)
router_main(const float* __restrict__ X, const float* __restrict__ noise,
            float* __restrict__ out, float* __restrict__ ws) {
  __shared__ __align__(16) float unbuf[4352];  // 2 x [32][68] staging; -> gcl/gnl
  __shared__ __align__(16) float Lg[2176];     // [32][68] logits; -> pl
  __shared__ float svs[32], sv2s[32];
  __shared__ float cntl[64];
  __shared__ float red8[8];
  float* gcl = unbuf;          // [32][68] clean gates (staging reads done)
  float* gnl = unbuf + 2176;   // [32][68] noisy gates
  float* pl  = Lg;             // per-lane read-then-write -> safe alias

  const int t = threadIdx.x;
  const int w = t >> 6, lane = t & 63;
  const int lrow = lane & 15, kh = lane >> 4;
  const int bid = blockIdx.x;
  const int s0 = bid * 4;

  // staging: thread t -> row r_t = t>>4 (32 rows), cols c_t..c_t+3 of 64-step
  const int r_t = t >> 4, c_t = (t & 15) * 4;
  const int ldso = r_t * 68 + c_t;
  const float* __restrict__ xstage =
      X + ((size_t)(r_t & 7) * S_ + (size_t)(s0 + (r_t >> 3))) * D_ + c_t;

  // GEMM: wave w -> rg = w>>2 (rows 16rg..16rg+15), et = w&3 (experts 16et..)
  const int rg = w >> 2, et = w & 3;
  const unsigned short* __restrict__ bp =
      (const unsigned short*)ws + (16 * et + lrow) * D_ + kh * 8;
  const float gwv = ws[WS_GW + 16 * et + lrow];
  const float bwv = ws[WS_BW + 16 * et + lrow];

  // epilogue indices + EARLY noise load (lands during GEMM)
  const int rr_e = lane >> 4, j_e = lane & 15;
  const int r_e = w * 4 + rr_e;                 // [0,32)
  const int b_e = r_e & 7, sl_e = r_e >> 3;
  const int s_e = s0 + sl_e;
  const float4 nv =
      *(const float4*)(noise + ((size_t)b_e * S_ + s_e) * E_ + 4 * j_e);

  // prologue: X regs for steps 0,1; B ring for steps 0,1; stage step 0
  float4 qx[2];
  short8 qb[2][2];
  qx[0] = *(const float4*)(xstage);
  qx[1] = *(const float4*)(xstage + 64);
  qb[0][0] = *(const short8*)(bp);
  qb[0][1] = *(const short8*)(bp + 32);
  qb[1][0] = *(const short8*)(bp + 64);
  qb[1][1] = *(const short8*)(bp + 96);

  float ssv = 0.0f, ssv2 = 0.0f;
  unbuf[ldso + 0] = qx[0].x; unbuf[ldso + 1] = qx[0].y;
  unbuf[ldso + 2] = qx[0].z; unbuf[ldso + 3] = qx[0].w;
  ssv  += (qx[0].x + qx[0].y) + (qx[0].z + qx[0].w);
  ssv2 = fmaf(qx[0].x, qx[0].x, ssv2); ssv2 = fmaf(qx[0].y, qx[0].y, ssv2);
  ssv2 = fmaf(qx[0].z, qx[0].z, ssv2); ssv2 = fmaf(qx[0].w, qx[0].w, ssv2);

  f32x4 acc = {0.f, 0.f, 0.f, 0.f};

#pragma unroll
  for (int s = 0; s < 16; ++s) {
    __syncthreads();                       // buf[s&1] staged
    if (s + 2 < 16)                        // X for step s+2 (slot s&1 now free)
      qx[s & 1] = *(const float4*)(xstage + (s + 2) * 64);

    const float* xb = unbuf + (s & 1) * 2176 + (16 * rg + lrow) * 68;
#pragma unroll
    for (int ks = 0; ks < 2; ++ks) {
      float4 a0 = *(const float4*)(xb + ks * 32 + kh * 8);
      float4 a1 = *(const float4*)(xb + ks * 32 + kh * 8 + 4);
      union { short8 s8; __hip_bfloat162 h[4]; } u;
      u.h[0] = __float22bfloat162_rn(make_float2(a0.x, a0.y));
      u.h[1] = __float22bfloat162_rn(make_float2(a0.z, a0.w));
      u.h[2] = __float22bfloat162_rn(make_float2(a1.x, a1.y));
      u.h[3] = __float22bfloat162_rn(make_float2(a1.z, a1.w));
      acc = __builtin_amdgcn_mfma_f32_16x16x32_bf16(u.s8, qb[s & 1][ks],
                                                    acc, 0, 0, 0);
    }
    if (s + 2 < 16) {                      // refill B ring slot just consumed
      qb[s & 1][0] = *(const short8*)(bp + (s + 2) * 64);
      qb[s & 1][1] = *(const short8*)(bp + (s + 2) * 64 + 32);
    }
    if (s + 1 < 16) {                      // stage step s+1 (issued at s-1)
      float4 wv = qx[(s + 1) & 1];
      float* d = unbuf + ((s + 1) & 1) * 2176 + ldso;
      d[0] = wv.x; d[1] = wv.y; d[2] = wv.z; d[3] = wv.w;
      ssv  += (wv.x + wv.y) + (wv.z + wv.w);
      ssv2 = fmaf(wv.x, wv.x, ssv2); ssv2 = fmaf(wv.y, wv.y, ssv2);
      ssv2 = fmaf(wv.z, wv.z, ssv2); ssv2 = fmaf(wv.w, wv.w, ssv2);
    }
  }

  // LN stats: 16 staging threads per row -> shfl reduce within 16-lane group
  ssv  += __shfl_xor(ssv, 1);  ssv  += __shfl_xor(ssv, 2);
  ssv  += __shfl_xor(ssv, 4);  ssv  += __shfl_xor(ssv, 8);
  ssv2 += __shfl_xor(ssv2, 1); ssv2 += __shfl_xor(ssv2, 2);
  ssv2 += __shfl_xor(ssv2, 4); ssv2 += __shfl_xor(ssv2, 8);
  if ((t & 15) == 0) { svs[r_t] = ssv; sv2s[r_t] = ssv2; }
  if (t < 64) cntl[t] = 0.0f;
  __syncthreads();

  // logits: C/D layout col=lane&15, row=(lane>>4)*4+i  [m89-verified]
#pragma unroll
  for (int i = 0; i < 4; i++) {
    const int rloc = 16 * rg + kh * 4 + i;
    const float mui = svs[rloc] * (1.0f / (float)D_);
    const float var = sv2s[rloc] * (1.0f / (float)D_) - mui * mui;
    const float rsi = rsqrtf(var + 1e-5f);
    Lg[rloc * 68 + 16 * et + lrow] = rsi * (acc[i] - mui * gwv) + bwv;
  }
  __syncthreads();   // logits ready; staging reads done -> gcl/gnl reusable

  // ---- epilogue: 8 waves; wave w rows 4w..4w+3; lane=(rr,j), 4 experts ----
  {
    const int r = r_e, b = b_e, s = s_e, j = j_e;
    float4 lv = *(const float4*)(Lg + r * 68 + 4 * j);
    float ln0 = fmaf(NOISE_STD, nv.x, lv.x);
    float ln1 = fmaf(NOISE_STD, nv.y, lv.y);
    float ln2 = fmaf(NOISE_STD, nv.z, lv.z);
    float ln3 = fmaf(NOISE_STD, nv.w, lv.w);

    // combined max+secondmax of noisy logits (m1 also shifts clean softmax)
    float m1 = ln0, m2 = -INFINITY;
    m2 = fmaxf(m2, fminf(m1, ln1)); m1 = fmaxf(m1, ln1);
    m2 = fmaxf(m2, fminf(m1, ln2)); m1 = fmaxf(m1, ln2);
    m2 = fmaxf(m2, fminf(m1, ln3)); m1 = fmaxf(m1, ln3);
#pragma unroll
    for (int o = 1; o <= 8; o <<= 1) {
      float o1 = __shfl_xor(m1, o), o2 = __shfl_xor(m2, o);
      m2 = fmaxf(fmaxf(m2, o2), fminf(m1, o1));
      m1 = fmaxf(m1, o1);
    }
    float ec0 = __expf(lv.x - m1), ec1 = __expf(lv.y - m1);
    float ec2 = __expf(lv.z - m1), ec3 = __expf(lv.w - m1);
    float en0 = __expf(ln0 - m1), en1 = __expf(ln1 - m1);
    float en2 = __expf(ln2 - m1), en3 = __expf(ln3 - m1);
    float sg = (ec0 + ec1) + (ec2 + ec3);
    float sn = (en0 + en1) + (en2 + en3);
#pragma unroll
    for (int o = 1; o <= 8; o <<= 1) {
      sg += __shfl_xor(sg, o);
      sn += __shfl_xor(sn, o);
    }
    const float rg_ = 1.0f / sg, rn_ = 1.0f / sn;
    float4 gnv = { en0 * rn_, en1 * rn_, en2 * rn_, en3 * rn_ };
    float4 gcv = { ec0 * rg_, ec1 * rg_, ec2 * rg_, ec3 * rg_ };
    float z0 = fminf(fmaxf((m2 - lv.x) * INV_NOISE_STD, -10.f), 10.f);
    float z1 = fminf(fmaxf((m2 - lv.y) * INV_NOISE_STD, -10.f), 10.f);
    float z2 = fminf(fmaxf((m2 - lv.z) * INV_NOISE_STD, -10.f), 10.f);
    float z3 = fminf(fmaxf((m2 - lv.w) * INV_NOISE_STD, -10.f), 10.f);
    float4 pv = { 0.5f * (1.0f + erff(z0 * 0.70710678118654752f)),
                  0.5f * (1.0f + erff(z1 * 0.70710678118654752f)),
                  0.5f * (1.0f + erff(z2 * 0.70710678118654752f)),
                  0.5f * (1.0f + erff(z3 * 0.70710678118654752f)) };

    *(float4*)(out + ((size_t)b * S_ + s) * E_ + 4 * j) = gnv;
    *(float4*)(gnl + r * 68 + 4 * j) = gnv;
    *(float4*)(gcl + r * 68 + 4 * j) = gcv;
    *(float4*)(pl  + r * 68 + 4 * j) = pv;
    // top-1 count via equality (ties vanishingly rare; softmax is monotone)
    if (ln0 == m1) atomicAdd(&cntl[4 * j + 0], 1.0f);
    if (ln1 == m1) atomicAdd(&cntl[4 * j + 1], 1.0f);
    if (ln2 == m1) atomicAdd(&cntl[4 * j + 2], 1.0f);
    if (ln3 == m1) atomicAdd(&cntl[4 * j + 3], 1.0f);
  }
  __syncthreads();

  // ---- phase 2: block reductions -> PLAIN per-block record (no atomics) ----
  float* prt = ws + WS_PART + (size_t)bid * PART_STRIDE;
  {
    // importance: thread t -> (b = t>>6, e = t&63), sum over 4 sl
    const int b0i = t >> 6, e0i = t & 63;
    float v = gcl[(0 * 8 + b0i) * 68 + e0i] + gcl[(1 * 8 + b0i) * 68 + e0i] +
              gcl[(2 * 8 + b0i) * 68 + e0i] + gcl[(3 * 8 + b0i) * 68 + e0i];
    prt[t] = v;
  }
  if (t < 64) {
    float sgn = 0.0f;
#pragma unroll
    for (int r = 0; r < 32; r++) sgn += gnl[r * 68 + t];
    prt[512 + t] = sgn;
  } else if (t < 128) {
    prt[576 + (t - 64)] = cntl[t - 64];
  } else if (t < 384) {
    const int idx = t - 128;            // [0,256): sl = idx>>6, e = idx&63
    const int slc = idx >> 6, e = idx & 63;
    float P = 0.0f;
#pragma unroll
    for (int b = 0; b < 8; b++) P += pl[(slc * 8 + b) * 68 + e];
    float c1 = P * 0.125f;
    float c2 = c1 * c1;
    c1 = wave_sum64(c1);
    c2 = wave_sum64(c2);
    if (lane == 0) { red8[(w - 2) * 2] = c1; red8[(w - 2) * 2 + 1] = c2; }
  }
  __syncthreads();
  if (t == 0) {
    prt[640] = (red8[0] + red8[2]) + (red8[4] + red8[6]);
    prt[641] = (red8[1] + red8[3]) + (red8[5] + red8[7]);
  }
}

// ---------------- reduce: 32 blocks x 32 records, deep unroll ---------------
__global__ void router_reduce(float* __restrict__ ws) {
  const int t = threadIdx.x;
  if (t >= N_TOT) return;
  const int base = blockIdx.x * 32;
  const float* p = ws + WS_PART + (size_t)base * PART_STRIDE + t;
  float acc = 0.0f;
#pragma unroll 8
  for (int i = 0; i < 32; ++i) acc += p[(size_t)i * PART_STRIDE];
  atomicAdd(&ws[WS_TOT + t], acc);
}

// ---------------- finalize: 3 scalar losses from totals ---------------------
__global__ void router_final(const float* __restrict__ ws, float* __restrict__ out) {
  const int lane = threadIdx.x;  // 64 threads = 1 wave
  const float* tot = ws + WS_TOT;
  float impsum = 0.0f;
  for (int b = 0; b < B_; ++b) {
    float v = tot[b * 64 + lane];
    float sfull = wave_sum64(v);
    float mean = sfull * (1.0f / 64.0f);
    float d = v - mean;
    float ss = wave_sum64(d * d);
    impsum += (ss / 63.0f) / (mean * mean);
  }
  float importance = impsum * (1.0f / (float)B_);

  const float N = (float)(S_ * E_);
  float meanp = tot[640] / N;
  float varp = tot[641] / N - meanp * meanp;
  float load = varp / (meanp * meanp);

  const float inv_rows = 1.0f / (float)(B_ * S_);
  float te = (tot[576 + lane] * inv_rows) * (tot[512 + lane] * inv_rows);
  float gs = wave_sum64(te) * (float)E_;

  if (lane == 0) {
    out[OUT_GATES + 0] = importance + load;  // aux (GSHARD_W = 0)
    out[OUT_GATES + 1] = gs;
    out[OUT_GATES + 2] = importance;
    out[OUT_GATES + 3] = load;
  }
}

extern "C" void kernel_launch(void* const* d_in, const int* in_sizes, int n_in,
                              void* d_out, int out_size, void* d_ws, size_t ws_size,
                              hipStream_t stream) {
  (void)in_sizes; (void)n_in; (void)out_size; (void)ws_size;
  const float* X     = (const float*)d_in[0];
  const float* noise = (const float*)d_in[1];
  const float* gamma = (const float*)d_in[2];
  const float* beta  = (const float*)d_in[3];
  const float* W     = (const float*)d_in[4];
  float* out = (float*)d_out;
  float* ws  = (float*)d_ws;

  router_prep<<<dim3(E_ + 1), dim3(256), 0, stream>>>(W, gamma, beta, ws);
  router_main<<<dim3(NBLK), dim3(512), 0, stream>>>(X, noise, out, ws);
  router_reduce<<<dim3(32), dim3(704), 0, stream>>>(ws);
  router_final<<<dim3(1), dim3(64), 0, stream>>>(ws, out);
}